// Round 1
// baseline (3148.855 us; speedup 1.0000x reference)
//
#include <hip/hip_runtime.h>
#include <hip/hip_bf16.h>
#include <math.h>

// Problem constants (from reference)
constexpr int S   = 512;
constexpr int D   = 2048;
constexpr int H   = 16;
constexpr int HD  = 128;
constexpr int T   = 512;     // B*S
constexpr int E   = 64;
constexpr int I_  = 512;
constexpr int G   = 8;
constexpr int TKG = 4;
constexpr int TK  = 6;
constexpr int SH_I = 1024;
constexpr float ROUTE_SCALE = 2.5f;
constexpr float EPS = 1e-5f;

// ---------------------------------------------------------------- rmsnorm
__global__ __launch_bounds__(256) void rmsnorm_kernel(const float* __restrict__ x,
                                                      const float* __restrict__ w,
                                                      float* __restrict__ out) {
    int t = blockIdx.x;
    int tid = threadIdx.x;
    const float* row = x + (size_t)t * D;
    float ss = 0.f;
    for (int i = tid; i < D; i += 256) { float v = row[i]; ss += v * v; }
    for (int o = 32; o; o >>= 1) ss += __shfl_down(ss, o, 64);
    __shared__ float red[4];
    if ((tid & 63) == 0) red[tid >> 6] = ss;
    __syncthreads();
    float tot = red[0] + red[1] + red[2] + red[3];
    float scale = rsqrtf(tot / (float)D + EPS);
    for (int i = tid; i < D; i += 256) out[(size_t)t * D + i] = row[i] * scale * w[i];
}

// ---------------------------------------------------------------- generic GEMM: C = A(MxK) @ B(NxK)^T (+ addsrc)
// Requires M%64==0, N%64==0, K%16==0.
__global__ __launch_bounds__(256) void gemm_nt_kernel(const float* __restrict__ A,
                                                      const float* __restrict__ B,
                                                      float* __restrict__ C,
                                                      const float* __restrict__ addsrc,
                                                      int M, int N, int K) {
    __shared__ float As[16][65];
    __shared__ float Bs[16][65];
    int m0 = blockIdx.y * 64, n0 = blockIdx.x * 64;
    int tid = threadIdx.x;
    int ty = tid >> 4, tx = tid & 15;
    int lm = tid >> 2, lk = (tid & 3) * 4;
    float c[4][4] = {};
    for (int k0 = 0; k0 < K; k0 += 16) {
        float4 av = *(const float4*)(A + (size_t)(m0 + lm) * K + k0 + lk);
        float4 bv = *(const float4*)(B + (size_t)(n0 + lm) * K + k0 + lk);
        As[lk + 0][lm] = av.x; As[lk + 1][lm] = av.y; As[lk + 2][lm] = av.z; As[lk + 3][lm] = av.w;
        Bs[lk + 0][lm] = bv.x; Bs[lk + 1][lm] = bv.y; Bs[lk + 2][lm] = bv.z; Bs[lk + 3][lm] = bv.w;
        __syncthreads();
#pragma unroll
        for (int kk = 0; kk < 16; kk++) {
            float a[4], b[4];
#pragma unroll
            for (int i = 0; i < 4; i++) a[i] = As[kk][ty * 4 + i];
#pragma unroll
            for (int j = 0; j < 4; j++) b[j] = Bs[kk][tx * 4 + j];
#pragma unroll
            for (int i = 0; i < 4; i++) {
#pragma unroll
                for (int j = 0; j < 4; j++) c[i][j] += a[i] * b[j];
            }
        }
        __syncthreads();
    }
#pragma unroll
    for (int i = 0; i < 4; i++) {
        int m = m0 + ty * 4 + i;
#pragma unroll
        for (int j = 0; j < 4; j++) {
            size_t off = (size_t)m * N + n0 + tx * 4 + j;
            C[off] = c[i][j] + (addsrc ? addsrc[off] : 0.f);
        }
    }
}

// ---------------------------------------------------------------- RoPE (in-place on q and k)
__global__ __launch_bounds__(256) void rope_kernel(float* __restrict__ q, float* __restrict__ k,
                                                   const float* __restrict__ fc,
                                                   const float* __restrict__ fs) {
    int idx = blockIdx.x * 256 + threadIdx.x;   // T*H*(HD/2)
    int p  = idx & (HD / 2 - 1);
    int hh = (idx >> 6) & (H - 1);
    int t  = idx >> 10;
    float c = fc[t * (HD / 2) + p], s = fs[t * (HD / 2) + p];
    size_t base = (size_t)t * D + hh * HD + p * 2;
    float re = q[base], im = q[base + 1];
    q[base]     = re * c - im * s;
    q[base + 1] = re * s + im * c;
    re = k[base]; im = k[base + 1];
    k[base]     = re * c - im * s;
    k[base + 1] = re * s + im * c;
}

// ---------------------------------------------------------------- attention: one block per (q-row, head)
__global__ __launch_bounds__(256) void attn_kernel(const float* __restrict__ q,
                                                   const float* __restrict__ k,
                                                   const float* __restrict__ v,
                                                   float* __restrict__ o) {
    int qi = blockIdx.x, hh = blockIdx.y, tid = threadIdx.x;
    __shared__ float qs[HD];
    __shared__ float sc[S];
    __shared__ float redm[4];
    __shared__ float redz[4];
    __shared__ float part[256];
    if (tid < HD) qs[tid] = q[(size_t)qi * D + hh * HD + tid];
    __syncthreads();
    int kn = qi + 1;            // causal: mask(-1e9) kills k>qi exactly after softmax
    float lmax = -1e30f;
    for (int kk = tid; kk < kn; kk += 256) {
        const float4* k4 = (const float4*)(k + (size_t)kk * D + hh * HD);
        const float4* q4 = (const float4*)qs;
        float s = 0.f;
#pragma unroll
        for (int d4 = 0; d4 < HD / 4; d4++) {
            float4 kvv = k4[d4], qvv = q4[d4];
            s += qvv.x * kvv.x + qvv.y * kvv.y + qvv.z * kvv.z + qvv.w * kvv.w;
        }
        s *= 0.08838834764831845f;   // 1/sqrt(128)
        sc[kk] = s;
        lmax = fmaxf(lmax, s);
    }
    for (int o2 = 32; o2; o2 >>= 1) lmax = fmaxf(lmax, __shfl_down(lmax, o2, 64));
    if ((tid & 63) == 0) redm[tid >> 6] = lmax;
    __syncthreads();
    float M_ = fmaxf(fmaxf(redm[0], redm[1]), fmaxf(redm[2], redm[3]));
    float lsum = 0.f;
    for (int kk = tid; kk < kn; kk += 256) {
        float e2 = expf(sc[kk] - M_);
        sc[kk] = e2;
        lsum += e2;
    }
    for (int o2 = 32; o2; o2 >>= 1) lsum += __shfl_down(lsum, o2, 64);
    if ((tid & 63) == 0) redz[tid >> 6] = lsum;
    __syncthreads();                  // also guarantees all sc[] writes visible
    float Z = redz[0] + redz[1] + redz[2] + redz[3];
    int d2 = tid & (HD - 1);
    int halfsel = tid >> 7;           // 0 or 1
    float acc = 0.f;
    for (int kk = halfsel; kk < kn; kk += 2)
        acc += sc[kk] * v[(size_t)kk * D + hh * HD + d2];
    part[tid] = acc;
    __syncthreads();
    if (tid < HD) o[(size_t)qi * D + hh * HD + tid] = (part[tid] + part[tid + HD]) / Z;
}

// ---------------------------------------------------------------- routing (sigmoid gate + group top-k + expert top-k)
__global__ __launch_bounds__(64) void routing_kernel(const float* __restrict__ logits,
                                                     float* __restrict__ gw,
                                                     int* __restrict__ counts,
                                                     int* __restrict__ elist) {
    int t = blockIdx.x;
    int lane = threadIdx.x;
    __shared__ float ss[E];
    if (lane < E) ss[lane] = 1.f / (1.f + expf(-logits[(size_t)t * E + lane]));
    __syncthreads();
    if (lane == 0) {
        float gs[G];
        for (int g = 0; g < G; g++) {
            float m = ss[g * 8];
            for (int j = 1; j < 8; j++) m = fmaxf(m, ss[g * 8 + j]);
            gs[g] = m;
        }
        bool keep[G];
        for (int g = 0; g < G; g++) keep[g] = false;
        for (int r = 0; r < TKG; r++) {
            int best = -1; float bv = -1e30f;
            for (int g = 0; g < G; g++)
                if (!keep[g] && gs[g] > bv) { bv = gs[g]; best = g; }
            keep[best] = true;
        }
        float masked[E];
        for (int e2 = 0; e2 < E; e2++) masked[e2] = keep[e2 >> 3] ? ss[e2] : -1e30f;
        int chosen[TK]; float w[TK]; float wsum = 0.f;
        for (int r = 0; r < TK; r++) {
            int best = 0; float bv = -1e31f;
            for (int e2 = 0; e2 < E; e2++)
                if (masked[e2] > bv) { bv = masked[e2]; best = e2; }
            chosen[r] = best; w[r] = ss[best]; masked[best] = -1e31f; wsum += w[r];
        }
        float scale_ = ROUTE_SCALE / wsum;
        for (int r = 0; r < TK; r++) {
            int slot = t * TK + r;
            gw[slot] = w[r] * scale_;
            int e2 = chosen[r];
            int pos = atomicAdd(&counts[e2], 1);
            elist[e2 * T + pos] = slot;
        }
    }
}

// ---------------------------------------------------------------- MoE up: a[slot, i] = silu(t@w1^T) * (t@w3^T), expert-grouped
__global__ __launch_bounds__(256) void moe_up_kernel(const float* __restrict__ tbuf,
                                                     const float* __restrict__ w1,
                                                     const float* __restrict__ w3,
                                                     const int* __restrict__ counts,
                                                     const int* __restrict__ elist,
                                                     float* __restrict__ abuf) {
    int e = blockIdx.x;
    int nt = counts[e];
    if (nt == 0) return;
    int i0 = blockIdx.y * 64;
    const float* W1 = w1 + (size_t)e * I_ * D;
    const float* W3 = w3 + (size_t)e * I_ * D;
    __shared__ float As[16][65], B1s[16][65], B3s[16][65];
    __shared__ int slots[64];
    int tid = threadIdx.x;
    int ty = tid >> 4, tx = tid & 15;
    int lm = tid >> 2, lk = (tid & 3) * 4;
    for (int tb = 0; tb < nt; tb += 64) {
        if (tid < 64) slots[tid] = (tb + tid < nt) ? elist[e * T + tb + tid] : -1;
        __syncthreads();
        int slm = slots[lm];
        const float* arow = (slm >= 0) ? (tbuf + (size_t)(slm / TK) * D) : nullptr;
        float c1[4][4] = {}, c3[4][4] = {};
        for (int k0 = 0; k0 < D; k0 += 16) {
            float4 av = arow ? *(const float4*)(arow + k0 + lk) : make_float4(0.f, 0.f, 0.f, 0.f);
            float4 b1 = *(const float4*)(W1 + (size_t)(i0 + lm) * D + k0 + lk);
            float4 b3 = *(const float4*)(W3 + (size_t)(i0 + lm) * D + k0 + lk);
            As[lk + 0][lm] = av.x; As[lk + 1][lm] = av.y; As[lk + 2][lm] = av.z; As[lk + 3][lm] = av.w;
            B1s[lk + 0][lm] = b1.x; B1s[lk + 1][lm] = b1.y; B1s[lk + 2][lm] = b1.z; B1s[lk + 3][lm] = b1.w;
            B3s[lk + 0][lm] = b3.x; B3s[lk + 1][lm] = b3.y; B3s[lk + 2][lm] = b3.z; B3s[lk + 3][lm] = b3.w;
            __syncthreads();
#pragma unroll
            for (int kk = 0; kk < 16; kk++) {
                float a[4], bb1[4], bb3[4];
#pragma unroll
                for (int i = 0; i < 4; i++) a[i] = As[kk][ty * 4 + i];
#pragma unroll
                for (int j = 0; j < 4; j++) { bb1[j] = B1s[kk][tx * 4 + j]; bb3[j] = B3s[kk][tx * 4 + j]; }
#pragma unroll
                for (int i = 0; i < 4; i++) {
#pragma unroll
                    for (int j = 0; j < 4; j++) {
                        c1[i][j] += a[i] * bb1[j];
                        c3[i][j] += a[i] * bb3[j];
                    }
                }
            }
            __syncthreads();
        }
#pragma unroll
        for (int i = 0; i < 4; i++) {
            int m = ty * 4 + i;
            if (tb + m < nt) {
                int sl = slots[m];
#pragma unroll
                for (int j = 0; j < 4; j++) {
                    float h1 = c1[i][j], h3v = c3[i][j];
                    float sil = h1 / (1.f + expf(-h1));
                    abuf[(size_t)sl * I_ + i0 + tx * 4 + j] = sil * h3v;
                }
            }
        }
        __syncthreads();
    }
}

// ---------------------------------------------------------------- MoE down: routed[t,:] += gw * a[slot,:] @ w2[e]^T
__global__ __launch_bounds__(256) void moe_down_kernel(const float* __restrict__ abuf,
                                                       const float* __restrict__ w2,
                                                       const int* __restrict__ counts,
                                                       const int* __restrict__ elist,
                                                       const float* __restrict__ gw,
                                                       float* __restrict__ routed) {
    int e = blockIdx.x;
    int nt = counts[e];
    if (nt == 0) return;
    int d0 = blockIdx.y * 64;
    const float* W2 = w2 + (size_t)e * D * I_;   // [d][i]
    __shared__ float As[16][65], Bs[16][65];
    __shared__ int slots[64];
    int tid = threadIdx.x;
    int ty = tid >> 4, tx = tid & 15;
    int lm = tid >> 2, lk = (tid & 3) * 4;
    for (int tb = 0; tb < nt; tb += 64) {
        if (tid < 64) slots[tid] = (tb + tid < nt) ? elist[e * T + tb + tid] : -1;
        __syncthreads();
        int slm = slots[lm];
        const float* arow = (slm >= 0) ? (abuf + (size_t)slm * I_) : nullptr;
        float c[4][4] = {};
        for (int k0 = 0; k0 < I_; k0 += 16) {
            float4 av = arow ? *(const float4*)(arow + k0 + lk) : make_float4(0.f, 0.f, 0.f, 0.f);
            float4 bv = *(const float4*)(W2 + (size_t)(d0 + lm) * I_ + k0 + lk);
            As[lk + 0][lm] = av.x; As[lk + 1][lm] = av.y; As[lk + 2][lm] = av.z; As[lk + 3][lm] = av.w;
            Bs[lk + 0][lm] = bv.x; Bs[lk + 1][lm] = bv.y; Bs[lk + 2][lm] = bv.z; Bs[lk + 3][lm] = bv.w;
            __syncthreads();
#pragma unroll
            for (int kk = 0; kk < 16; kk++) {
                float a[4], b[4];
#pragma unroll
                for (int i = 0; i < 4; i++) a[i] = As[kk][ty * 4 + i];
#pragma unroll
                for (int j = 0; j < 4; j++) b[j] = Bs[kk][tx * 4 + j];
#pragma unroll
                for (int i = 0; i < 4; i++) {
#pragma unroll
                    for (int j = 0; j < 4; j++) c[i][j] += a[i] * b[j];
                }
            }
            __syncthreads();
        }
#pragma unroll
        for (int i = 0; i < 4; i++) {
            int m = ty * 4 + i;
            if (tb + m < nt) {
                int sl = slots[m];
                float g = gw[sl];
                int t = sl / TK;
#pragma unroll
                for (int j = 0; j < 4; j++)
                    atomicAdd(&routed[(size_t)t * D + d0 + tx * 4 + j], g * c[i][j]);
            }
        }
        __syncthreads();
    }
}

// ---------------------------------------------------------------- elementwise
__global__ __launch_bounds__(256) void silu_mul_kernel(const float* __restrict__ a,
                                                       const float* __restrict__ b,
                                                       float* __restrict__ o, int n) {
    int i = blockIdx.x * 256 + threadIdx.x;
    if (i < n) { float x = a[i]; o[i] = x / (1.f + expf(-x)) * b[i]; }
}

__global__ __launch_bounds__(256) void add_inplace_kernel(float* __restrict__ o,
                                                          const float* __restrict__ a, int n) {
    int i = blockIdx.x * 256 + threadIdx.x;
    if (i < n) o[i] += a[i];
}

// ---------------------------------------------------------------- launch
extern "C" void kernel_launch(void* const* d_in, const int* in_sizes, int n_in,
                              void* d_out, int out_size, void* d_ws, size_t ws_size,
                              hipStream_t stream) {
    (void)in_sizes; (void)n_in; (void)out_size; (void)ws_size;
    const float* x      = (const float*)d_in[0];
    const float* fc     = (const float*)d_in[1];
    const float* fs     = (const float*)d_in[2];
    // d_in[3] mask: causality handled analytically
    const float* anw    = (const float*)d_in[4];
    const float* fnw    = (const float*)d_in[5];
    const float* wq     = (const float*)d_in[6];
    const float* wk     = (const float*)d_in[7];
    const float* wv     = (const float*)d_in[8];
    const float* wo     = (const float*)d_in[9];
    const float* gate_w = (const float*)d_in[10];
    const float* ew1    = (const float*)d_in[11];
    const float* ew2    = (const float*)d_in[12];
    const float* ew3    = (const float*)d_in[13];
    const float* sw1    = (const float*)d_in[14];
    const float* sw2    = (const float*)d_in[15];
    const float* sw3    = (const float*)d_in[16];
    float* out = (float*)d_out;

    char* wsp = (char*)d_ws;
    size_t off = 0;
    auto alloc = [&](size_t bytes) {
        void* p = wsp + off;
        off += (bytes + 255) & ~(size_t)255;
        return p;
    };
    float* hbuf   = (float*)alloc((size_t)T * D * 4);
    float* qbuf   = (float*)alloc((size_t)T * D * 4);
    float* kbuf   = (float*)alloc((size_t)T * D * 4);
    float* vbuf   = (float*)alloc((size_t)T * D * 4);
    float* attnb  = (float*)alloc((size_t)T * D * 4);
    float* x1     = (float*)alloc((size_t)T * D * 4);
    float* tbuf   = (float*)alloc((size_t)T * D * 4);
    float* routed = (float*)alloc((size_t)T * D * 4);
    float* logits = (float*)alloc((size_t)T * E * 4);
    float* gwbuf  = (float*)alloc((size_t)T * TK * 4);
    int*   counts = (int*)alloc(E * 4);
    int*   elist  = (int*)alloc((size_t)E * T * 4);
    float* abuf   = (float*)alloc((size_t)T * TK * I_ * 4);
    float* u1     = (float*)alloc((size_t)T * SH_I * 4);
    float* u3     = (float*)alloc((size_t)T * SH_I * 4);
    float* ub     = (float*)alloc((size_t)T * SH_I * 4);

    hipMemsetAsync(counts, 0, E * 4, stream);
    hipMemsetAsync(routed, 0, (size_t)T * D * 4, stream);

    // attention branch
    rmsnorm_kernel<<<T, 256, 0, stream>>>(x, anw, hbuf);
    dim3 gDD(D / 64, T / 64);
    gemm_nt_kernel<<<gDD, 256, 0, stream>>>(hbuf, wq, qbuf, nullptr, T, D, D);
    gemm_nt_kernel<<<gDD, 256, 0, stream>>>(hbuf, wk, kbuf, nullptr, T, D, D);
    gemm_nt_kernel<<<gDD, 256, 0, stream>>>(hbuf, wv, vbuf, nullptr, T, D, D);
    rope_kernel<<<(T * H * HD / 2) / 256, 256, 0, stream>>>(qbuf, kbuf, fc, fs);
    attn_kernel<<<dim3(S, H), 256, 0, stream>>>(qbuf, kbuf, vbuf, attnb);
    gemm_nt_kernel<<<gDD, 256, 0, stream>>>(attnb, wo, x1, x, T, D, D);

    // FFN branch
    rmsnorm_kernel<<<T, 256, 0, stream>>>(x1, fnw, tbuf);
    gemm_nt_kernel<<<dim3(1, T / 64), 256, 0, stream>>>(tbuf, gate_w, logits, nullptr, T, E, D);
    routing_kernel<<<T, 64, 0, stream>>>(logits, gwbuf, counts, elist);
    moe_up_kernel<<<dim3(E, I_ / 64), 256, 0, stream>>>(tbuf, ew1, ew3, counts, elist, abuf);
    moe_down_kernel<<<dim3(E, D / 64), 256, 0, stream>>>(abuf, ew2, counts, elist, gwbuf, routed);

    gemm_nt_kernel<<<dim3(SH_I / 64, T / 64), 256, 0, stream>>>(tbuf, sw1, u1, nullptr, T, SH_I, D);
    gemm_nt_kernel<<<dim3(SH_I / 64, T / 64), 256, 0, stream>>>(tbuf, sw3, u3, nullptr, T, SH_I, D);
    silu_mul_kernel<<<(T * SH_I) / 256, 256, 0, stream>>>(u1, u3, ub, T * SH_I);
    gemm_nt_kernel<<<dim3(D / 64, T / 64), 256, 0, stream>>>(ub, sw2, out, x1, T, D, SH_I);
    add_inplace_kernel<<<(T * D) / 256, 256, 0, stream>>>(out, routed, T * D);
}